// Round 9
// baseline (555.163 us; speedup 1.0000x reference)
//
#include <hip/hip_runtime.h>
#include <math.h>

#define BB 4
#define TT 2048
#define HH 12
#define DD 64
#define HID 768
#define RR 512
#define T2 1536
#define TH 1024   // T/2
#define UNM 512   // TH - R
#define SCALEF 0.125f

typedef short bf8v __attribute__((ext_vector_type(8)));
typedef float f4v  __attribute__((ext_vector_type(4)));

// float -> bf16 round-to-nearest-even
__device__ inline short f2bf(float f) {
    unsigned u = __float_as_uint(f);
    u += 0x7fffu + ((u >> 16) & 1u);
    return (short)(u >> 16);
}

// ---------------------------------------------------------------------------
// fp32 tiled GEMM (index path ONLY): C = A@W + bias. Sequential-K fp32 chain
// per output element (bit-exact vs the reference-matching r4 kernel: same
// single accumulator, same k ascending order, same fused a*b contraction).
// 128x128 tile, BK=16, 256 threads, 8x8 per thread -> 64 FMA : 4 ds_read_b128.
// ---------------------------------------------------------------------------
__global__ __launch_bounds__(256) void gemm_bias(const float* __restrict__ A,
                                                 const float* __restrict__ Wt,
                                                 const float* __restrict__ bias,
                                                 float* __restrict__ C,
                                                 int M, int N, int K) {
    __shared__ float As[16][132];   // transposed A tile, padded
    __shared__ float Bs[16][128];
    int tid = threadIdx.x;
    int n0 = blockIdx.x * 128, m0 = blockIdx.y * 128;
    int tx = tid & 15, ty = tid >> 4;          // tx->n (8 cols), ty->m (8 rows)
    int la_m = tid >> 1, la_k = (tid & 1) << 3;
    int lb_k = tid >> 4, lb_n = (tid & 15) << 3;
    const float* ag = A + (size_t)(m0 + la_m) * K + la_k;
    const float* bg = Wt + (size_t)lb_k * N + n0 + lb_n;
    float acc[8][8] = {};
    for (int k0 = 0; k0 < K; k0 += 16) {
        float4 av0 = *(const float4*)(ag + k0);
        float4 av1 = *(const float4*)(ag + k0 + 4);
        float4 bv0 = *(const float4*)(bg + (size_t)k0 * N);
        float4 bv1 = *(const float4*)(bg + (size_t)k0 * N + 4);
        __syncthreads();
        As[la_k + 0][la_m] = av0.x; As[la_k + 1][la_m] = av0.y;
        As[la_k + 2][la_m] = av0.z; As[la_k + 3][la_m] = av0.w;
        As[la_k + 4][la_m] = av1.x; As[la_k + 5][la_m] = av1.y;
        As[la_k + 6][la_m] = av1.z; As[la_k + 7][la_m] = av1.w;
        *(float4*)&Bs[lb_k][lb_n] = bv0;
        *(float4*)&Bs[lb_k][lb_n + 4] = bv1;
        __syncthreads();
#pragma unroll
        for (int kk = 0; kk < 16; kk++) {
            float4 a0 = *(const float4*)&As[kk][ty << 3];
            float4 a1 = *(const float4*)&As[kk][(ty << 3) + 4];
            float4 b0 = *(const float4*)&Bs[kk][tx << 3];
            float4 b1 = *(const float4*)&Bs[kk][(tx << 3) + 4];
            float ar[8] = {a0.x, a0.y, a0.z, a0.w, a1.x, a1.y, a1.z, a1.w};
            float br[8] = {b0.x, b0.y, b0.z, b0.w, b1.x, b1.y, b1.z, b1.w};
#pragma unroll
            for (int i = 0; i < 8; i++)
#pragma unroll
                for (int j = 0; j < 8; j++) acc[i][j] += ar[i] * br[j];
        }
    }
    float4 bva = *(const float4*)(bias + n0 + (tx << 3));
    float4 bvb = *(const float4*)(bias + n0 + (tx << 3) + 4);
    float bb8[8] = {bva.x, bva.y, bva.z, bva.w, bvb.x, bvb.y, bvb.z, bvb.w};
#pragma unroll
    for (int i = 0; i < 8; i++) {
        int m = m0 + (ty << 3) + i;
        float4 v0, v1;
        v0.x = acc[i][0] + bb8[0]; v0.y = acc[i][1] + bb8[1];
        v0.z = acc[i][2] + bb8[2]; v0.w = acc[i][3] + bb8[3];
        v1.x = acc[i][4] + bb8[4]; v1.y = acc[i][5] + bb8[5];
        v1.z = acc[i][6] + bb8[6]; v1.w = acc[i][7] + bb8[7];
        *(float4*)(C + (size_t)m * N + n0 + (tx << 3)) = v0;
        *(float4*)(C + (size_t)m * N + n0 + (tx << 3) + 4) = v1;
    }
}

// ---------------------------------------------------------------------------
// Weight transpose + bf16 convert: Wt_b[n][k] = bf16(W[k][n]). 4 matrices.
// ---------------------------------------------------------------------------
struct WPtrs {
    const float* w[4];
    short* wt[4];
};

__global__ __launch_bounds__(256) void transpose_w_kernel(WPtrs p) {
    __shared__ short tile[64][65];
    const float* W = p.w[blockIdx.z];
    short* Wt = p.wt[blockIdx.z];
    int k0 = blockIdx.x * 64, n0 = blockIdx.y * 64;
    int tid = threadIdx.x;
#pragma unroll
    for (int i = 0; i < 16; i++) {
        int idx = tid + i * 256;
        int r = idx >> 6, c = idx & 63;
        tile[c][r] = f2bf(W[(size_t)(k0 + r) * HID + n0 + c]);
    }
    __syncthreads();
#pragma unroll
    for (int i = 0; i < 16; i++) {
        int idx = tid + i * 256;
        int r = idx >> 6, c = idx & 63;
        Wt[(size_t)(n0 + r) * HID + k0 + c] = tile[r][c];
    }
}

// fp32 -> bf16 elementwise (float4 granularity)
__global__ __launch_bounds__(256) void f32_to_bf16_kernel(const float* __restrict__ in,
                                                          short* __restrict__ out, int n4) {
    int i = blockIdx.x * 256 + threadIdx.x;
    if (i >= n4) return;
    float4 v = ((const float4*)in)[i];
    short4 s;
    s.x = f2bf(v.x); s.y = f2bf(v.y); s.z = f2bf(v.z); s.w = f2bf(v.w);
    ((short4*)out)[i] = s;
}

// ---------------------------------------------------------------------------
// bf16 MFMA GEMM: C = A[M,768] @ B[768,768] + bias, B given transposed bf16
// (Bt[n][k]). 128x128 tile, BK=32, 4 waves (2x2 of 64x64), 16 MFMA/wave/iter.
// fp32 accumulate. Epilogue modes:
//  0: fp32 out + res (res==C aliasing safe)   [out-proj]
//  1: bf16 out row-major                      [k]
//  2: bf16 out transposed per head [B,H,D,T2] [v]
//  3: bf16 out row-major, scaled by 0.125     [q]
// ---------------------------------------------------------------------------
__global__ __launch_bounds__(256) void gemm_mfma(const short* __restrict__ A,
                                                 const short* __restrict__ Bt,
                                                 const float* __restrict__ bias,
                                                 const float* __restrict__ res,
                                                 void* __restrict__ Cout,
                                                 int M, int mode) {
    __shared__ short As[128][40];
    __shared__ short Bs[128][40];
    int tid = threadIdx.x;
    int m0 = blockIdx.y * 128, n0 = blockIdx.x * 128;
    int w = tid >> 6, lane = tid & 63, quad = lane >> 4, l = lane & 15;
    int wm = (w & 1) << 6, wn = (w >> 1) << 6;

    f4v acc[4][4];
#pragma unroll
    for (int i = 0; i < 4; i++)
#pragma unroll
        for (int j = 0; j < 4; j++) acc[i][j] = (f4v){0.f, 0.f, 0.f, 0.f};

    int srow = tid >> 1, sseg = (tid & 1) << 4;
    const short* ag = A + (size_t)(m0 + srow) * HID + sseg;
    const short* bg = Bt + (size_t)(n0 + srow) * HID + sseg;

    for (int k0 = 0; k0 < HID; k0 += 32) {
        __syncthreads();
        *(bf8v*)&As[srow][sseg]     = *(const bf8v*)(ag + k0);
        *(bf8v*)&As[srow][sseg + 8] = *(const bf8v*)(ag + k0 + 8);
        *(bf8v*)&Bs[srow][sseg]     = *(const bf8v*)(bg + k0);
        *(bf8v*)&Bs[srow][sseg + 8] = *(const bf8v*)(bg + k0 + 8);
        __syncthreads();
        bf8v af[4], bfv[4];
#pragma unroll
        for (int mt = 0; mt < 4; mt++) af[mt] = *(const bf8v*)&As[wm + mt * 16 + l][quad * 8];
#pragma unroll
        for (int nt = 0; nt < 4; nt++) bfv[nt] = *(const bf8v*)&Bs[wn + nt * 16 + l][quad * 8];
#pragma unroll
        for (int mt = 0; mt < 4; mt++)
#pragma unroll
            for (int nt = 0; nt < 4; nt++)
                acc[mt][nt] = __builtin_amdgcn_mfma_f32_16x16x32_bf16(af[mt], bfv[nt], acc[mt][nt], 0, 0, 0);
    }

    float bia[4];
#pragma unroll
    for (int nt = 0; nt < 4; nt++) bia[nt] = bias[n0 + wn + nt * 16 + l];

    if (mode == 0) {
        float* C = (float*)Cout;
#pragma unroll
        for (int mt = 0; mt < 4; mt++)
#pragma unroll
            for (int r = 0; r < 4; r++) {
                int m = m0 + wm + mt * 16 + quad * 4 + r;
#pragma unroll
                for (int nt = 0; nt < 4; nt++) {
                    int n = n0 + wn + nt * 16 + l;
                    C[(size_t)m * HID + n] = acc[mt][nt][r] + bia[nt] + res[(size_t)m * HID + n];
                }
            }
    } else if (mode == 1 || mode == 3) {
        short* C = (short*)Cout;
        float sc = (mode == 3) ? SCALEF : 1.0f;
#pragma unroll
        for (int mt = 0; mt < 4; mt++)
#pragma unroll
            for (int r = 0; r < 4; r++) {
                int m = m0 + wm + mt * 16 + quad * 4 + r;
#pragma unroll
                for (int nt = 0; nt < 4; nt++) {
                    int n = n0 + wn + nt * 16 + l;
                    C[(size_t)m * HID + n] = f2bf((acc[mt][nt][r] + bia[nt]) * sc);
                }
            }
    } else {
        short* C = (short*)Cout;
#pragma unroll
        for (int nt = 0; nt < 4; nt++) {
            int n = n0 + wn + nt * 16 + l;
            int h = n >> 6, d = n & 63;
#pragma unroll
            for (int mt = 0; mt < 4; mt++) {
                int m = m0 + wm + mt * 16 + quad * 4;
                int b = m / T2, t = m % T2;
                short4 sv;
                sv.x = f2bf(acc[mt][nt][0] + bia[nt]);
                sv.y = f2bf(acc[mt][nt][1] + bia[nt]);
                sv.z = f2bf(acc[mt][nt][2] + bia[nt]);
                sv.w = f2bf(acc[mt][nt][3] + bia[nt]);
                *(short4*)(C + (((size_t)b * HH + h) * DD + d) * T2 + t) = sv;
            }
        }
    }
}

// ---------------------------------------------------------------------------
// metric mean: metric[t,d] = (sum_{h} k[t, h*64+d]) / 12  (fp32, h ascending)
// ---------------------------------------------------------------------------
__global__ __launch_bounds__(256) void metric_mean_kernel(const float* __restrict__ k32,
                                                          float* __restrict__ metric) {
    int idx = blockIdx.x * 256 + threadIdx.x;
    if (idx >= BB * TT * DD) return;
    int t = idx >> 6, d = idx & 63;
    float s = 0.f;
#pragma unroll
    for (int h = 0; h < HH; h++) s += k32[(size_t)t * HID + h * DD + d];
    metric[idx] = s / 12.0f;
}

__global__ __launch_bounds__(256) void metric_normalize_kernel(float* __restrict__ metric) {
    int row = blockIdx.x * 256 + threadIdx.x;
    if (row >= BB * TT) return;
    float* p = metric + (size_t)row * DD;
    float ss = 0.f;
#pragma unroll
    for (int d = 0; d < DD; d++) ss += p[d] * p[d];
    float denom = sqrtf(ss) + 1e-6f;
#pragma unroll
    for (int d = 0; d < DD; d++) p[d] = p[d] / denom;
}

// ---------------------------------------------------------------------------
// Partial scores: grid (8 j-splits, 16 i-tiles, B), block 256 (4 waves).
// ---------------------------------------------------------------------------
__global__ __launch_bounds__(256) void tome_scores_part_kernel(const float* __restrict__ metric,
                                                               float* __restrict__ part_max,
                                                               int* __restrict__ part_idx) {
    int b = blockIdx.z;
    int i0 = blockIdx.y * 64;
    int jbase = blockIdx.x * 128;
    int tid = threadIdx.x;
    int il = tid & 63, w = tid >> 6;
    __shared__ float b_lds[64][68];

    const float* arow = metric + ((size_t)b * TT + 2 * (i0 + il)) * DD;
    float4 areg[16];
#pragma unroll
    for (int t = 0; t < 16; t++) areg[t] = ((const float4*)arow)[t];

    float best = -INFINITY;
    int bidx = 0;
    for (int c = 0; c < 2; c++) {
        __syncthreads();
        {
            int r = tid >> 2, cb = (tid & 3) << 4;
            const float* src = metric + ((size_t)b * TT + 2 * (jbase + c * 64 + r) + 1) * DD + cb;
#pragma unroll
            for (int t = 0; t < 4; t++)
                *(float4*)&b_lds[r][cb + 4 * t] = ((const float4*)src)[t];
        }
        __syncthreads();
#pragma unroll
        for (int jj = 0; jj < 16; jj++) {
            int jr = w * 16 + jj;
            float acc = 0.f;
#pragma unroll
            for (int t = 0; t < 16; t++) {
                float4 bv = *(const float4*)&b_lds[jr][t * 4];
                acc += areg[t].x * bv.x;
                acc += areg[t].y * bv.y;
                acc += areg[t].z * bv.z;
                acc += areg[t].w * bv.w;
            }
            int j = jbase + c * 64 + jr;
            if (acc > best) { best = acc; bidx = j; }
        }
    }
    int slot = ((b * TH + i0 + il) << 5) + (blockIdx.x << 2) + w;
    part_max[slot] = best;
    part_idx[slot] = bidx;
}

__global__ __launch_bounds__(1024) void tome_scores_combine_kernel(const float* __restrict__ part_max,
                                                                   const int* __restrict__ part_idx,
                                                                   float* __restrict__ node_max,
                                                                   int* __restrict__ node_idx) {
    int b = blockIdx.x, i = threadIdx.x;
    int base = (b * TH + i) << 5;
    float bv = part_max[base];
    int bi = part_idx[base];
#pragma unroll
    for (int p = 1; p < 32; p++) {
        float v = part_max[base + p];
        int vi = part_idx[base + p];
        if (v > bv || (v == bv && vi < bi)) { bv = v; bi = vi; }
    }
    node_max[b * TH + i] = bv;
    node_idx[b * TH + i] = bi;
}

// ---------------------------------------------------------------------------
// Stable descending argsort via rank counting. grid B, block 1024.
// ---------------------------------------------------------------------------
__global__ __launch_bounds__(1024) void tome_order_kernel(const float* __restrict__ node_max,
                                                          const int* __restrict__ node_idx,
                                                          int* __restrict__ dst_idx,
                                                          int* __restrict__ src_tok,
                                                          int* __restrict__ unm_tok) {
    __shared__ float vals[TH];
    int b = blockIdx.x;
    int i = threadIdx.x;
    vals[i] = node_max[b * TH + i];
    __syncthreads();
    float v = vals[i];
    int rank = 0;
    for (int j = 0; j < TH; j++) {
        float vj = vals[j];
        rank += (vj > v || (vj == v && j < i)) ? 1 : 0;
    }
    if (rank < RR) {
        src_tok[b * RR + rank] = i;
        dst_idx[b * RR + rank] = node_idx[b * TH + i];
    } else {
        unm_tok[b * UNM + (rank - RR)] = i;
    }
}

__global__ __launch_bounds__(1024) void tome_counts_kernel(const int* __restrict__ dst_idx,
                                                           int* __restrict__ counts) {
    __shared__ int c[TH];
    int b = blockIdx.x;
    int i = threadIdx.x;
    c[i] = 0;
    __syncthreads();
    if (i < RR) atomicAdd(&c[dst_idx[b * RR + i]], 1);
    __syncthreads();
    counts[b * TH + i] = c[i];
}

// ---------------------------------------------------------------------------
// Merge hidden only (merge commutes with affine maps; avg weights sum to 1).
// ---------------------------------------------------------------------------
__global__ __launch_bounds__(192) void merge_base_kernel(const float* __restrict__ in,
                                                         float* __restrict__ out,
                                                         const int* __restrict__ unm_tok) {
    int t = blockIdx.x, b = blockIdx.y;
    int src_row = (t < UNM) ? 2 * unm_tok[b * UNM + t] : 2 * (t - UNM) + 1;
    const float4* src = (const float4*)(in + ((size_t)b * TT + src_row) * HID);
    float4* dst = (float4*)(out + ((size_t)b * T2 + t) * HID);
    dst[threadIdx.x] = src[threadIdx.x];
}

__global__ __launch_bounds__(256) void merge_scatter_kernel(const float* __restrict__ in,
                                                            float* __restrict__ out,
                                                            const int* __restrict__ src_tok,
                                                            const int* __restrict__ dst_idx) {
    int s = blockIdx.x, b = blockIdx.y;
    int srow = 2 * src_tok[b * RR + s];
    int drow = UNM + dst_idx[b * RR + s];
    const float* src = in + ((size_t)b * TT + srow) * HID;
    float* dst = out + ((size_t)b * T2 + drow) * HID;
#pragma unroll
    for (int c = threadIdx.x; c < HID; c += 256) atomicAdd(&dst[c], src[c]);
}

__global__ __launch_bounds__(256) void merge_scale_kernel(float* __restrict__ out,
                                                          const int* __restrict__ counts) {
    int r = blockIdx.x, b = blockIdx.y;
    float inv = 1.0f / (1.0f + (float)counts[b * TH + r]);
    float* dst = out + ((size_t)b * T2 + UNM + r) * HID;
#pragma unroll
    for (int c = threadIdx.x; c < HID; c += 256) dst[c] *= inv;
}

// ---------------------------------------------------------------------------
// MFMA bf16 flash attention, transposed form (S^T / O^T). All-bf16 I/O.
// ---------------------------------------------------------------------------
__global__ __launch_bounds__(256) void attn_mfma_kernel(short* __restrict__ qmb,
                                                        const short* __restrict__ kmb,
                                                        const short* __restrict__ vtb) {
    __shared__ short Ks[64][72];
    __shared__ short Vts[64][72];
    __shared__ short Pt[4][16][72];

    const int b = blockIdx.z, h = blockIdx.y;
    const int tid = threadIdx.x;
    const int w = tid >> 6;
    const int lane = tid & 63;
    const int quad = lane >> 4;
    const int l = lane & 15;
    const int q0 = blockIdx.x * 64 + w * 16;

    short* qp = qmb + ((size_t)b * T2 + q0 + l) * HID + h * DD;
    bf8v bq0 = *(const bf8v*)(qp + quad * 8);
    bf8v bq1 = *(const bf8v*)(qp + 32 + quad * 8);

    f4v O[4];
#pragma unroll
    for (int t = 0; t < 4; t++) O[t] = (f4v){0.f, 0.f, 0.f, 0.f};
    float m_st = -INFINITY, l_st = 0.f;

    const int rstg = tid >> 2;
    const int cstg = (tid & 3) << 4;
    const short* kbase = kmb + (size_t)b * T2 * HID + h * DD;
    const short* vbase = vtb + (((size_t)b * HH + h) * DD + rstg) * T2;

    for (int c0 = 0; c0 < T2; c0 += 64) {
        __syncthreads();
        {
            const short* ksrc = kbase + (size_t)(c0 + rstg) * HID + cstg;
            *(bf8v*)&Ks[rstg][cstg]     = *(const bf8v*)ksrc;
            *(bf8v*)&Ks[rstg][cstg + 8] = *(const bf8v*)(ksrc + 8);
            const short* vsrc = vbase + c0 + cstg;
            *(bf8v*)&Vts[rstg][cstg]     = *(const bf8v*)vsrc;
            *(bf8v*)&Vts[rstg][cstg + 8] = *(const bf8v*)(vsrc + 8);
        }
        __syncthreads();

        f4v s[4];
#pragma unroll
        for (int t = 0; t < 4; t++) {
            bf8v ak0 = *(const bf8v*)&Ks[t * 16 + l][quad * 8];
            bf8v ak1 = *(const bf8v*)&Ks[t * 16 + l][32 + quad * 8];
            f4v acc = (f4v){0.f, 0.f, 0.f, 0.f};
            acc = __builtin_amdgcn_mfma_f32_16x16x32_bf16(ak0, bq0, acc, 0, 0, 0);
            acc = __builtin_amdgcn_mfma_f32_16x16x32_bf16(ak1, bq1, acc, 0, 0, 0);
            s[t] = acc;
        }

        float mx = s[0][0];
#pragma unroll
        for (int t = 0; t < 4; t++)
#pragma unroll
            for (int r = 0; r < 4; r++) mx = fmaxf(mx, s[t][r]);
        mx = fmaxf(mx, __shfl_xor(mx, 16));
        mx = fmaxf(mx, __shfl_xor(mx, 32));
        float mnew = fmaxf(m_st, mx);
        float alpha = __expf(m_st - mnew);
        float p[4][4];
        float sum = 0.f;
#pragma unroll
        for (int t = 0; t < 4; t++)
#pragma unroll
            for (int r = 0; r < 4; r++) {
                float pv = __expf(s[t][r] - mnew);
                p[t][r] = pv;
                sum += pv;
            }
        sum += __shfl_xor(sum, 16);
        sum += __shfl_xor(sum, 32);
        l_st = l_st * alpha + sum;
        m_st = mnew;
#pragma unroll
        for (int t = 0; t < 4; t++) {
            O[t][0] *= alpha; O[t][1] *= alpha; O[t][2] *= alpha; O[t][3] *= alpha;
        }

#pragma unroll
        for (int t = 0; t < 4; t++) {
            short4 pv;
            pv.x = f2bf(p[t][0]); pv.y = f2bf(p[t][1]);
            pv.z = f2bf(p[t][2]); pv.w = f2bf(p[t][3]);
            *(short4*)&Pt[w][l][t * 16 + quad * 4] = pv;
        }

        {
            bf8v bp0 = *(const bf8v*)&Pt[w][l][quad * 8];
            bf8v bp1 = *(const bf8v*)&Pt[w][l][32 + quad * 8];
#pragma unroll
            for (int t = 0; t < 4; t++) {
                bf8v av0 = *(const bf8v*)&Vts[t * 16 + l][quad * 8];
                bf8v av1 = *(const bf8v*)&Vts[t * 16 + l][32 + quad * 8];
                O[t] = __builtin_amdgcn_mfma_f32_16x16x32_bf16(av0, bp0, O[t], 0, 0, 0);
                O[t] = __builtin_amdgcn_mfma_f32_16x16x32_bf16(av1, bp1, O[t], 0, 0, 0);
            }
        }
    }

    float inv = 1.0f / l_st;
#pragma unroll
    for (int t = 0; t < 4; t++) {
        short4 ov;
        ov.x = f2bf(O[t][0] * inv); ov.y = f2bf(O[t][1] * inv);
        ov.z = f2bf(O[t][2] * inv); ov.w = f2bf(O[t][3] * inv);
        *(short4*)(qp + t * 16 + quad * 4) = ov;
    }
}

// ---------------------------------------------------------------------------
// LayerNorm in place: grid B*T2 rows, block 256 (each thread 3 cols)
// ---------------------------------------------------------------------------
__global__ __launch_bounds__(256) void ln_kernel(float* __restrict__ out,
                                                 const float* __restrict__ gamma,
                                                 const float* __restrict__ beta) {
    int row = blockIdx.x;
    int tid = threadIdx.x;
    float* p = out + (size_t)row * HID;
    float x[3];
#pragma unroll
    for (int i = 0; i < 3; i++) x[i] = p[tid + i * 256];
    float s = x[0] + x[1] + x[2];
#pragma unroll
    for (int off = 1; off < 64; off <<= 1) s += __shfl_xor(s, off);
    __shared__ float sb[4];
    int wid = tid >> 6;
    if ((tid & 63) == 0) sb[wid] = s;
    __syncthreads();
    float mu = (sb[0] + sb[1] + sb[2] + sb[3]) * (1.0f / HID);
    float vs = 0.f;
#pragma unroll
    for (int i = 0; i < 3; i++) {
        float d = x[i] - mu;
        vs += d * d;
    }
#pragma unroll
    for (int off = 1; off < 64; off <<= 1) vs += __shfl_xor(vs, off);
    __syncthreads();
    if ((tid & 63) == 0) sb[wid] = vs;
    __syncthreads();
    float var = (sb[0] + sb[1] + sb[2] + sb[3]) * (1.0f / HID);
    float inv = rsqrtf(var + 1e-12f);
#pragma unroll
    for (int i = 0; i < 3; i++) {
        int c = tid + i * 256;
        p[c] = (x[i] - mu) * inv * gamma[c] + beta[c];
    }
}

// ---------------------------------------------------------------------------
extern "C" void kernel_launch(void* const* d_in, const int* in_sizes, int n_in,
                              void* d_out, int out_size, void* d_ws, size_t ws_size,
                              hipStream_t stream) {
    const float* hidden = (const float*)d_in[0];
    const float* Wq = (const float*)d_in[1];
    const float* bq = (const float*)d_in[2];
    const float* Wk = (const float*)d_in[3];
    const float* bk = (const float*)d_in[4];
    const float* Wv = (const float*)d_in[5];
    const float* bv = (const float*)d_in[6];
    const float* Wo = (const float*)d_in[7];
    const float* bo = (const float*)d_in[8];
    const float* gamma = (const float*)d_in[9];
    const float* beta = (const float*)d_in[10];

    const size_t SZ_MERG = (size_t)BB * T2 * HID;    // 4718592 elements
    short* qmb = (short*)d_ws;                        // bf16 q (scaled) / ctx
    short* kmb = qmb + SZ_MERG;                       // bf16 k row-major
    short* vtb = kmb + SZ_MERG;                       // bf16 v^T [B,H,D,T2]
    short* rmb = vtb + SZ_MERG;                       // bf16 merged hidden
    short* wqb = rmb + SZ_MERG;                       // bf16 W^T [N,K] x4
    short* wkb = wqb + HID * HID;
    short* wvb = wkb + HID * HID;
    short* wob = wvb + HID * HID;
    float* k32 = (float*)d_ws;                        // fp32 k (25.2MB) overlaps
                                                      // qmb..vtb; dead by step 8
    float* metric = (float*)(wob + HID * HID);        // B*T*64 fp32
    float* node_max = metric + (size_t)BB * TT * DD;
    int* node_idx = (int*)(node_max + BB * TH);
    int* dst_idx = node_idx + BB * TH;
    int* src_tok = dst_idx + BB * RR;
    int* unm_tok = src_tok + BB * RR;
    int* counts = unm_tok + BB * UNM;
    float* part_max = (float*)(counts + BB * TH);
    int* part_idx = (int*)(part_max + (size_t)BB * TH * 32);
    float* rm = (float*)d_out;                        // merged residual in d_out

    // 0. weight transpose+bf16 (independent; wqb.. does NOT overlap k32)
    WPtrs wp;
    wp.w[0] = Wq; wp.w[1] = Wk; wp.w[2] = Wv; wp.w[3] = Wo;
    wp.wt[0] = wqb; wp.wt[1] = wkb; wp.wt[2] = wvb; wp.wt[3] = wob;
    transpose_w_kernel<<<dim3(HID / 64, HID / 64, 4), 256, 0, stream>>>(wp);

    // 1. full k = hidden @ Wk + bk (fp32, sequential-K chain — index path)
    gemm_bias<<<dim3(HID / 128, BB * TT / 128), 256, 0, stream>>>(hidden, Wk, bk, k32, BB * TT, HID, HID);

    // 2-3. metric = head-mean of k, then row-normalize (fp32)
    metric_mean_kernel<<<(BB * TT * DD + 255) / 256, 256, 0, stream>>>(k32, metric);
    metric_normalize_kernel<<<(BB * TT + 255) / 256, 256, 0, stream>>>(metric);

    // 4. scores -> partial (max, argmax), then combine
    tome_scores_part_kernel<<<dim3(8, 16, BB), 256, 0, stream>>>(metric, part_max, part_idx);
    tome_scores_combine_kernel<<<BB, 1024, 0, stream>>>(part_max, part_idx, node_max, node_idx);

    // 5-6. stable order + counts
    tome_order_kernel<<<BB, 1024, 0, stream>>>(node_max, node_idx, dst_idx, src_tok, unm_tok);
    tome_counts_kernel<<<BB, 1024, 0, stream>>>(dst_idx, counts);

    // 7. merge hidden -> rm (residual, in d_out); then bf16 copy
    merge_base_kernel<<<dim3(T2, BB), 192, 0, stream>>>(hidden, rm, unm_tok);
    merge_scatter_kernel<<<dim3(RR, BB), 256, 0, stream>>>(hidden, rm, src_tok, dst_idx);
    merge_scale_kernel<<<dim3(TH, BB), 256, 0, stream>>>(rm, counts);
    f32_to_bf16_kernel<<<(int)((SZ_MERG / 4 + 255) / 256), 256, 0, stream>>>(rm, rmb, (int)(SZ_MERG / 4));

    // 8. QKV projections via bf16 MFMA (q scaled+bf16, k bf16, v bf16-T)
    gemm_mfma<<<dim3(HID / 128, BB * T2 / 128), 256, 0, stream>>>(rmb, wqb, bq, nullptr, qmb, BB * T2, 3);
    gemm_mfma<<<dim3(HID / 128, BB * T2 / 128), 256, 0, stream>>>(rmb, wkb, bk, nullptr, kmb, BB * T2, 1);
    gemm_mfma<<<dim3(HID / 128, BB * T2 / 128), 256, 0, stream>>>(rmb, wvb, bv, nullptr, vtb, BB * T2, 2);

    // 9. MFMA flash attention (all-bf16 I/O), ctx in place of q
    attn_mfma_kernel<<<dim3(T2 / 64, HH, BB), 256, 0, stream>>>(qmb, kmb, vtb);

    // 10. out = ctx @ Wo + bo + residual (fp32 epilogue; res==C alias safe)
    gemm_mfma<<<dim3(HID / 128, BB * T2 / 128), 256, 0, stream>>>(qmb, wob, bo, rm, d_out, BB * T2, 0);

    // 11. LayerNorm in place
    ln_kernel<<<BB * T2, 256, 0, stream>>>((float*)d_out, gamma, beta);
}

// Round 10
// 550.424 us; speedup vs baseline: 1.0086x; 1.0086x over previous
//
#include <hip/hip_runtime.h>
#include <math.h>

#define BB 4
#define TT 2048
#define HH 12
#define DD 64
#define HID 768
#define RR 512
#define T2 1536
#define TH 1024   // T/2
#define UNM 512   // TH - R
#define SCALEF 0.125f

typedef short bf8v __attribute__((ext_vector_type(8)));
typedef float f4v  __attribute__((ext_vector_type(4)));

// float -> bf16 round-to-nearest-even
__device__ inline short f2bf(float f) {
    unsigned u = __float_as_uint(f);
    u += 0x7fffu + ((u >> 16) & 1u);
    return (short)(u >> 16);
}

// ---------------------------------------------------------------------------
// fp32 tiled GEMM (index path ONLY): C = A@W + bias. Sequential-K fp32 chain
// per output element (bit-exact: single accumulator, kk ascending).
// 128x128 tile, BK=16, 256 threads, 8x8/thread in FOUR 4x4 quadrants
// (m in {ty*4, 64+ty*4}, n in {tx*4, 64+tx*4}) -> all LDS frag reads are
// float4 with <=2-way bank aliasing. Global loads for tile k0+16 are issued
// before the barriers of tile k0 (register prefetch).
// ---------------------------------------------------------------------------
__global__ __launch_bounds__(256) void gemm_bias(const float* __restrict__ A,
                                                 const float* __restrict__ Wt,
                                                 const float* __restrict__ bias,
                                                 float* __restrict__ C,
                                                 int M, int N, int K) {
    __shared__ float As[16][132];   // transposed A tile (k, m), padded
    __shared__ float Bs[16][132];   // B tile (k, n), padded
    int tid = threadIdx.x;
    int n0 = blockIdx.x * 128, m0 = blockIdx.y * 128;
    int tx = tid & 15, ty = tid >> 4;
    int la_m = tid >> 1, la_k = (tid & 1) << 3;
    int lb_k = tid >> 4, lb_n = (tid & 15) << 3;
    const float* ag = A + (size_t)(m0 + la_m) * K + la_k;
    const float* bg = Wt + (size_t)lb_k * N + n0 + lb_n;

    float acc[8][8] = {};
    float4 a0n = *(const float4*)(ag);
    float4 a1n = *(const float4*)(ag + 4);
    float4 b0n = *(const float4*)(bg);
    float4 b1n = *(const float4*)(bg + 4);

    for (int k0 = 0; k0 < K; k0 += 16) {
        float4 av0 = a0n, av1 = a1n, bv0 = b0n, bv1 = b1n;
        if (k0 + 16 < K) {
            a0n = *(const float4*)(ag + k0 + 16);
            a1n = *(const float4*)(ag + k0 + 20);
            b0n = *(const float4*)(bg + (size_t)(k0 + 16) * N);
            b1n = *(const float4*)(bg + (size_t)(k0 + 16) * N + 4);
        }
        __syncthreads();
        As[la_k + 0][la_m] = av0.x; As[la_k + 1][la_m] = av0.y;
        As[la_k + 2][la_m] = av0.z; As[la_k + 3][la_m] = av0.w;
        As[la_k + 4][la_m] = av1.x; As[la_k + 5][la_m] = av1.y;
        As[la_k + 6][la_m] = av1.z; As[la_k + 7][la_m] = av1.w;
        *(float4*)&Bs[lb_k][lb_n] = bv0;
        *(float4*)&Bs[lb_k][lb_n + 4] = bv1;
        __syncthreads();
#pragma unroll
        for (int kk = 0; kk < 16; kk++) {
            float4 a0 = *(const float4*)&As[kk][ty << 2];
            float4 a1 = *(const float4*)&As[kk][64 + (ty << 2)];
            float4 b0 = *(const float4*)&Bs[kk][tx << 2];
            float4 b1 = *(const float4*)&Bs[kk][64 + (tx << 2)];
            float ar[8] = {a0.x, a0.y, a0.z, a0.w, a1.x, a1.y, a1.z, a1.w};
            float br[8] = {b0.x, b0.y, b0.z, b0.w, b1.x, b1.y, b1.z, b1.w};
#pragma unroll
            for (int i = 0; i < 8; i++)
#pragma unroll
                for (int j = 0; j < 8; j++) acc[i][j] += ar[i] * br[j];
        }
    }
    float4 bva = *(const float4*)(bias + n0 + (tx << 2));
    float4 bvb = *(const float4*)(bias + n0 + 64 + (tx << 2));
    float bb8[8] = {bva.x, bva.y, bva.z, bva.w, bvb.x, bvb.y, bvb.z, bvb.w};
#pragma unroll
    for (int i = 0; i < 8; i++) {
        int m = m0 + ((i < 4) ? ((ty << 2) + i) : (64 + (ty << 2) + i - 4));
        float4 v0, v1;
        v0.x = acc[i][0] + bb8[0]; v0.y = acc[i][1] + bb8[1];
        v0.z = acc[i][2] + bb8[2]; v0.w = acc[i][3] + bb8[3];
        v1.x = acc[i][4] + bb8[4]; v1.y = acc[i][5] + bb8[5];
        v1.z = acc[i][6] + bb8[6]; v1.w = acc[i][7] + bb8[7];
        *(float4*)(C + (size_t)m * N + n0 + (tx << 2)) = v0;
        *(float4*)(C + (size_t)m * N + n0 + 64 + (tx << 2)) = v1;
    }
}

// ---------------------------------------------------------------------------
// Weight transpose + bf16 convert: Wt_b[n][k] = bf16(W[k][n]). 4 matrices.
// ---------------------------------------------------------------------------
struct WPtrs {
    const float* w[4];
    short* wt[4];
};

__global__ __launch_bounds__(256) void transpose_w_kernel(WPtrs p) {
    __shared__ short tile[64][65];
    const float* W = p.w[blockIdx.z];
    short* Wt = p.wt[blockIdx.z];
    int k0 = blockIdx.x * 64, n0 = blockIdx.y * 64;
    int tid = threadIdx.x;
#pragma unroll
    for (int i = 0; i < 16; i++) {
        int idx = tid + i * 256;
        int r = idx >> 6, c = idx & 63;
        tile[c][r] = f2bf(W[(size_t)(k0 + r) * HID + n0 + c]);
    }
    __syncthreads();
#pragma unroll
    for (int i = 0; i < 16; i++) {
        int idx = tid + i * 256;
        int r = idx >> 6, c = idx & 63;
        Wt[(size_t)(n0 + r) * HID + k0 + c] = tile[r][c];
    }
}

// fp32 -> bf16 elementwise (float4 granularity)
__global__ __launch_bounds__(256) void f32_to_bf16_kernel(const float* __restrict__ in,
                                                          short* __restrict__ out, int n4) {
    int i = blockIdx.x * 256 + threadIdx.x;
    if (i >= n4) return;
    float4 v = ((const float4*)in)[i];
    short4 s;
    s.x = f2bf(v.x); s.y = f2bf(v.y); s.z = f2bf(v.z); s.w = f2bf(v.w);
    ((short4*)out)[i] = s;
}

// ---------------------------------------------------------------------------
// bf16 MFMA GEMM: C = A[M,768] @ B[768,768] + bias, B given transposed bf16.
// 128x128 tile, BK=32, 4 waves. Epilogue modes 0..3 (see r8).
// ---------------------------------------------------------------------------
__global__ __launch_bounds__(256) void gemm_mfma(const short* __restrict__ A,
                                                 const short* __restrict__ Bt,
                                                 const float* __restrict__ bias,
                                                 const float* __restrict__ res,
                                                 void* __restrict__ Cout,
                                                 int M, int mode) {
    __shared__ short As[128][40];
    __shared__ short Bs[128][40];
    int tid = threadIdx.x;
    int m0 = blockIdx.y * 128, n0 = blockIdx.x * 128;
    int w = tid >> 6, lane = tid & 63, quad = lane >> 4, l = lane & 15;
    int wm = (w & 1) << 6, wn = (w >> 1) << 6;

    f4v acc[4][4];
#pragma unroll
    for (int i = 0; i < 4; i++)
#pragma unroll
        for (int j = 0; j < 4; j++) acc[i][j] = (f4v){0.f, 0.f, 0.f, 0.f};

    int srow = tid >> 1, sseg = (tid & 1) << 4;
    const short* ag = A + (size_t)(m0 + srow) * HID + sseg;
    const short* bg = Bt + (size_t)(n0 + srow) * HID + sseg;

    for (int k0 = 0; k0 < HID; k0 += 32) {
        __syncthreads();
        *(bf8v*)&As[srow][sseg]     = *(const bf8v*)(ag + k0);
        *(bf8v*)&As[srow][sseg + 8] = *(const bf8v*)(ag + k0 + 8);
        *(bf8v*)&Bs[srow][sseg]     = *(const bf8v*)(bg + k0);
        *(bf8v*)&Bs[srow][sseg + 8] = *(const bf8v*)(bg + k0 + 8);
        __syncthreads();
        bf8v af[4], bfv[4];
#pragma unroll
        for (int mt = 0; mt < 4; mt++) af[mt] = *(const bf8v*)&As[wm + mt * 16 + l][quad * 8];
#pragma unroll
        for (int nt = 0; nt < 4; nt++) bfv[nt] = *(const bf8v*)&Bs[wn + nt * 16 + l][quad * 8];
#pragma unroll
        for (int mt = 0; mt < 4; mt++)
#pragma unroll
            for (int nt = 0; nt < 4; nt++)
                acc[mt][nt] = __builtin_amdgcn_mfma_f32_16x16x32_bf16(af[mt], bfv[nt], acc[mt][nt], 0, 0, 0);
    }

    float bia[4];
#pragma unroll
    for (int nt = 0; nt < 4; nt++) bia[nt] = bias[n0 + wn + nt * 16 + l];

    if (mode == 0) {
        float* C = (float*)Cout;
#pragma unroll
        for (int mt = 0; mt < 4; mt++)
#pragma unroll
            for (int r = 0; r < 4; r++) {
                int m = m0 + wm + mt * 16 + quad * 4 + r;
#pragma unroll
                for (int nt = 0; nt < 4; nt++) {
                    int n = n0 + wn + nt * 16 + l;
                    C[(size_t)m * HID + n] = acc[mt][nt][r] + bia[nt] + res[(size_t)m * HID + n];
                }
            }
    } else if (mode == 1 || mode == 3) {
        short* C = (short*)Cout;
        float sc = (mode == 3) ? SCALEF : 1.0f;
#pragma unroll
        for (int mt = 0; mt < 4; mt++)
#pragma unroll
            for (int r = 0; r < 4; r++) {
                int m = m0 + wm + mt * 16 + quad * 4 + r;
#pragma unroll
                for (int nt = 0; nt < 4; nt++) {
                    int n = n0 + wn + nt * 16 + l;
                    C[(size_t)m * HID + n] = f2bf((acc[mt][nt][r] + bia[nt]) * sc);
                }
            }
    } else {
        short* C = (short*)Cout;
#pragma unroll
        for (int nt = 0; nt < 4; nt++) {
            int n = n0 + wn + nt * 16 + l;
            int h = n >> 6, d = n & 63;
#pragma unroll
            for (int mt = 0; mt < 4; mt++) {
                int m = m0 + wm + mt * 16 + quad * 4;
                int b = m / T2, t = m % T2;
                short4 sv;
                sv.x = f2bf(acc[mt][nt][0] + bia[nt]);
                sv.y = f2bf(acc[mt][nt][1] + bia[nt]);
                sv.z = f2bf(acc[mt][nt][2] + bia[nt]);
                sv.w = f2bf(acc[mt][nt][3] + bia[nt]);
                *(short4*)(C + (((size_t)b * HH + h) * DD + d) * T2 + t) = sv;
            }
        }
    }
}

// ---------------------------------------------------------------------------
// metric mean: metric[t,d] = (sum_{h} k[t, h*64+d]) / 12  (fp32, h ascending)
// ---------------------------------------------------------------------------
__global__ __launch_bounds__(256) void metric_mean_kernel(const float* __restrict__ k32,
                                                          float* __restrict__ metric) {
    int idx = blockIdx.x * 256 + threadIdx.x;
    if (idx >= BB * TT * DD) return;
    int t = idx >> 6, d = idx & 63;
    float s = 0.f;
#pragma unroll
    for (int h = 0; h < HH; h++) s += k32[(size_t)t * HID + h * DD + d];
    metric[idx] = s / 12.0f;
}

__global__ __launch_bounds__(256) void metric_normalize_kernel(float* __restrict__ metric) {
    int row = blockIdx.x * 256 + threadIdx.x;
    if (row >= BB * TT) return;
    float* p = metric + (size_t)row * DD;
    float ss = 0.f;
#pragma unroll
    for (int d = 0; d < DD; d++) ss += p[d] * p[d];
    float denom = sqrtf(ss) + 1e-6f;
#pragma unroll
    for (int d = 0; d < DD; d++) p[d] = p[d] / denom;
}

// ---------------------------------------------------------------------------
// Partial scores: grid (8 j-splits, 16 i-tiles, B), block 256 (4 waves).
// ---------------------------------------------------------------------------
__global__ __launch_bounds__(256) void tome_scores_part_kernel(const float* __restrict__ metric,
                                                               float* __restrict__ part_max,
                                                               int* __restrict__ part_idx) {
    int b = blockIdx.z;
    int i0 = blockIdx.y * 64;
    int jbase = blockIdx.x * 128;
    int tid = threadIdx.x;
    int il = tid & 63, w = tid >> 6;
    __shared__ float b_lds[64][68];

    const float* arow = metric + ((size_t)b * TT + 2 * (i0 + il)) * DD;
    float4 areg[16];
#pragma unroll
    for (int t = 0; t < 16; t++) areg[t] = ((const float4*)arow)[t];

    float best = -INFINITY;
    int bidx = 0;
    for (int c = 0; c < 2; c++) {
        __syncthreads();
        {
            int r = tid >> 2, cb = (tid & 3) << 4;
            const float* src = metric + ((size_t)b * TT + 2 * (jbase + c * 64 + r) + 1) * DD + cb;
#pragma unroll
            for (int t = 0; t < 4; t++)
                *(float4*)&b_lds[r][cb + 4 * t] = ((const float4*)src)[t];
        }
        __syncthreads();
#pragma unroll
        for (int jj = 0; jj < 16; jj++) {
            int jr = w * 16 + jj;
            float acc = 0.f;
#pragma unroll
            for (int t = 0; t < 16; t++) {
                float4 bv = *(const float4*)&b_lds[jr][t * 4];
                acc += areg[t].x * bv.x;
                acc += areg[t].y * bv.y;
                acc += areg[t].z * bv.z;
                acc += areg[t].w * bv.w;
            }
            int j = jbase + c * 64 + jr;
            if (acc > best) { best = acc; bidx = j; }
        }
    }
    int slot = ((b * TH + i0 + il) << 5) + (blockIdx.x << 2) + w;
    part_max[slot] = best;
    part_idx[slot] = bidx;
}

__global__ __launch_bounds__(1024) void tome_scores_combine_kernel(const float* __restrict__ part_max,
                                                                   const int* __restrict__ part_idx,
                                                                   float* __restrict__ node_max,
                                                                   int* __restrict__ node_idx) {
    int b = blockIdx.x, i = threadIdx.x;
    int base = (b * TH + i) << 5;
    float bv = part_max[base];
    int bi = part_idx[base];
#pragma unroll
    for (int p = 1; p < 32; p++) {
        float v = part_max[base + p];
        int vi = part_idx[base + p];
        if (v > bv || (v == bv && vi < bi)) { bv = v; bi = vi; }
    }
    node_max[b * TH + i] = bv;
    node_idx[b * TH + i] = bi;
}

// ---------------------------------------------------------------------------
// Stable descending argsort via rank counting. grid B, block 1024.
// ---------------------------------------------------------------------------
__global__ __launch_bounds__(1024) void tome_order_kernel(const float* __restrict__ node_max,
                                                          const int* __restrict__ node_idx,
                                                          int* __restrict__ dst_idx,
                                                          int* __restrict__ src_tok,
                                                          int* __restrict__ unm_tok) {
    __shared__ float vals[TH];
    int b = blockIdx.x;
    int i = threadIdx.x;
    vals[i] = node_max[b * TH + i];
    __syncthreads();
    float v = vals[i];
    int rank = 0;
    for (int j = 0; j < TH; j++) {
        float vj = vals[j];
        rank += (vj > v || (vj == v && j < i)) ? 1 : 0;
    }
    if (rank < RR) {
        src_tok[b * RR + rank] = i;
        dst_idx[b * RR + rank] = node_idx[b * TH + i];
    } else {
        unm_tok[b * UNM + (rank - RR)] = i;
    }
}

__global__ __launch_bounds__(1024) void tome_counts_kernel(const int* __restrict__ dst_idx,
                                                           int* __restrict__ counts) {
    __shared__ int c[TH];
    int b = blockIdx.x;
    int i = threadIdx.x;
    c[i] = 0;
    __syncthreads();
    if (i < RR) atomicAdd(&c[dst_idx[b * RR + i]], 1);
    __syncthreads();
    counts[b * TH + i] = c[i];
}

// ---------------------------------------------------------------------------
// Merge hidden only (merge commutes with affine maps; avg weights sum to 1).
// ---------------------------------------------------------------------------
__global__ __launch_bounds__(192) void merge_base_kernel(const float* __restrict__ in,
                                                         float* __restrict__ out,
                                                         const int* __restrict__ unm_tok) {
    int t = blockIdx.x, b = blockIdx.y;
    int src_row = (t < UNM) ? 2 * unm_tok[b * UNM + t] : 2 * (t - UNM) + 1;
    const float4* src = (const float4*)(in + ((size_t)b * TT + src_row) * HID);
    float4* dst = (float4*)(out + ((size_t)b * T2 + t) * HID);
    dst[threadIdx.x] = src[threadIdx.x];
}

__global__ __launch_bounds__(256) void merge_scatter_kernel(const float* __restrict__ in,
                                                            float* __restrict__ out,
                                                            const int* __restrict__ src_tok,
                                                            const int* __restrict__ dst_idx) {
    int s = blockIdx.x, b = blockIdx.y;
    int srow = 2 * src_tok[b * RR + s];
    int drow = UNM + dst_idx[b * RR + s];
    const float* src = in + ((size_t)b * TT + srow) * HID;
    float* dst = out + ((size_t)b * T2 + drow) * HID;
#pragma unroll
    for (int c = threadIdx.x; c < HID; c += 256) atomicAdd(&dst[c], src[c]);
}

__global__ __launch_bounds__(256) void merge_scale_kernel(float* __restrict__ out,
                                                          const int* __restrict__ counts) {
    int r = blockIdx.x, b = blockIdx.y;
    float inv = 1.0f / (1.0f + (float)counts[b * TH + r]);
    float* dst = out + ((size_t)b * T2 + UNM + r) * HID;
#pragma unroll
    for (int c = threadIdx.x; c < HID; c += 256) dst[c] *= inv;
}

// ---------------------------------------------------------------------------
// MFMA bf16 flash attention, transposed form (S^T / O^T). All-bf16 I/O.
// ---------------------------------------------------------------------------
__global__ __launch_bounds__(256) void attn_mfma_kernel(short* __restrict__ qmb,
                                                        const short* __restrict__ kmb,
                                                        const short* __restrict__ vtb) {
    __shared__ short Ks[64][72];
    __shared__ short Vts[64][72];
    __shared__ short Pt[4][16][72];

    const int b = blockIdx.z, h = blockIdx.y;
    const int tid = threadIdx.x;
    const int w = tid >> 6;
    const int lane = tid & 63;
    const int quad = lane >> 4;
    const int l = lane & 15;
    const int q0 = blockIdx.x * 64 + w * 16;

    short* qp = qmb + ((size_t)b * T2 + q0 + l) * HID + h * DD;
    bf8v bq0 = *(const bf8v*)(qp + quad * 8);
    bf8v bq1 = *(const bf8v*)(qp + 32 + quad * 8);

    f4v O[4];
#pragma unroll
    for (int t = 0; t < 4; t++) O[t] = (f4v){0.f, 0.f, 0.f, 0.f};
    float m_st = -INFINITY, l_st = 0.f;

    const int rstg = tid >> 2;
    const int cstg = (tid & 3) << 4;
    const short* kbase = kmb + (size_t)b * T2 * HID + h * DD;
    const short* vbase = vtb + (((size_t)b * HH + h) * DD + rstg) * T2;

    for (int c0 = 0; c0 < T2; c0 += 64) {
        __syncthreads();
        {
            const short* ksrc = kbase + (size_t)(c0 + rstg) * HID + cstg;
            *(bf8v*)&Ks[rstg][cstg]     = *(const bf8v*)ksrc;
            *(bf8v*)&Ks[rstg][cstg + 8] = *(const bf8v*)(ksrc + 8);
            const short* vsrc = vbase + c0 + cstg;
            *(bf8v*)&Vts[rstg][cstg]     = *(const bf8v*)vsrc;
            *(bf8v*)&Vts[rstg][cstg + 8] = *(const bf8v*)(vsrc + 8);
        }
        __syncthreads();

        f4v s[4];
#pragma unroll
        for (int t = 0; t < 4; t++) {
            bf8v ak0 = *(const bf8v*)&Ks[t * 16 + l][quad * 8];
            bf8v ak1 = *(const bf8v*)&Ks[t * 16 + l][32 + quad * 8];
            f4v acc = (f4v){0.f, 0.f, 0.f, 0.f};
            acc = __builtin_amdgcn_mfma_f32_16x16x32_bf16(ak0, bq0, acc, 0, 0, 0);
            acc = __builtin_amdgcn_mfma_f32_16x16x32_bf16(ak1, bq1, acc, 0, 0, 0);
            s[t] = acc;
        }

        float mx = s[0][0];
#pragma unroll
        for (int t = 0; t < 4; t++)
#pragma unroll
            for (int r = 0; r < 4; r++) mx = fmaxf(mx, s[t][r]);
        mx = fmaxf(mx, __shfl_xor(mx, 16));
        mx = fmaxf(mx, __shfl_xor(mx, 32));
        float mnew = fmaxf(m_st, mx);
        float alpha = __expf(m_st - mnew);
        float p[4][4];
        float sum = 0.f;
#pragma unroll
        for (int t = 0; t < 4; t++)
#pragma unroll
            for (int r = 0; r < 4; r++) {
                float pv = __expf(s[t][r] - mnew);
                p[t][r] = pv;
                sum += pv;
            }
        sum += __shfl_xor(sum, 16);
        sum += __shfl_xor(sum, 32);
        l_st = l_st * alpha + sum;
        m_st = mnew;
#pragma unroll
        for (int t = 0; t < 4; t++) {
            O[t][0] *= alpha; O[t][1] *= alpha; O[t][2] *= alpha; O[t][3] *= alpha;
        }

#pragma unroll
        for (int t = 0; t < 4; t++) {
            short4 pv;
            pv.x = f2bf(p[t][0]); pv.y = f2bf(p[t][1]);
            pv.z = f2bf(p[t][2]); pv.w = f2bf(p[t][3]);
            *(short4*)&Pt[w][l][t * 16 + quad * 4] = pv;
        }

        {
            bf8v bp0 = *(const bf8v*)&Pt[w][l][quad * 8];
            bf8v bp1 = *(const bf8v*)&Pt[w][l][32 + quad * 8];
#pragma unroll
            for (int t = 0; t < 4; t++) {
                bf8v av0 = *(const bf8v*)&Vts[t * 16 + l][quad * 8];
                bf8v av1 = *(const bf8v*)&Vts[t * 16 + l][32 + quad * 8];
                O[t] = __builtin_amdgcn_mfma_f32_16x16x32_bf16(av0, bp0, O[t], 0, 0, 0);
                O[t] = __builtin_amdgcn_mfma_f32_16x16x32_bf16(av1, bp1, O[t], 0, 0, 0);
            }
        }
    }

    float inv = 1.0f / l_st;
#pragma unroll
    for (int t = 0; t < 4; t++) {
        short4 ov;
        ov.x = f2bf(O[t][0] * inv); ov.y = f2bf(O[t][1] * inv);
        ov.z = f2bf(O[t][2] * inv); ov.w = f2bf(O[t][3] * inv);
        *(short4*)(qp + t * 16 + quad * 4) = ov;
    }
}

// ---------------------------------------------------------------------------
// LayerNorm in place: grid B*T2 rows, block 256 (each thread 3 cols)
// ---------------------------------------------------------------------------
__global__ __launch_bounds__(256) void ln_kernel(float* __restrict__ out,
                                                 const float* __restrict__ gamma,
                                                 const float* __restrict__ beta) {
    int row = blockIdx.x;
    int tid = threadIdx.x;
    float* p = out + (size_t)row * HID;
    float x[3];
#pragma unroll
    for (int i = 0; i < 3; i++) x[i] = p[tid + i * 256];
    float s = x[0] + x[1] + x[2];
#pragma unroll
    for (int off = 1; off < 64; off <<= 1) s += __shfl_xor(s, off);
    __shared__ float sb[4];
    int wid = tid >> 6;
    if ((tid & 63) == 0) sb[wid] = s;
    __syncthreads();
    float mu = (sb[0] + sb[1] + sb[2] + sb[3]) * (1.0f / HID);
    float vs = 0.f;
#pragma unroll
    for (int i = 0; i < 3; i++) {
        float d = x[i] - mu;
        vs += d * d;
    }
#pragma unroll
    for (int off = 1; off < 64; off <<= 1) vs += __shfl_xor(vs, off);
    __syncthreads();
    if ((tid & 63) == 0) sb[wid] = vs;
    __syncthreads();
    float var = (sb[0] + sb[1] + sb[2] + sb[3]) * (1.0f / HID);
    float inv = rsqrtf(var + 1e-12f);
#pragma unroll
    for (int i = 0; i < 3; i++) {
        int c = tid + i * 256;
        p[c] = (x[i] - mu) * inv * gamma[c] + beta[c];
    }
}

// ---------------------------------------------------------------------------
extern "C" void kernel_launch(void* const* d_in, const int* in_sizes, int n_in,
                              void* d_out, int out_size, void* d_ws, size_t ws_size,
                              hipStream_t stream) {
    const float* hidden = (const float*)d_in[0];
    const float* Wq = (const float*)d_in[1];
    const float* bq = (const float*)d_in[2];
    const float* Wk = (const float*)d_in[3];
    const float* bk = (const float*)d_in[4];
    const float* Wv = (const float*)d_in[5];
    const float* bv = (const float*)d_in[6];
    const float* Wo = (const float*)d_in[7];
    const float* bo = (const float*)d_in[8];
    const float* gamma = (const float*)d_in[9];
    const float* beta = (const float*)d_in[10];

    const size_t SZ_MERG = (size_t)BB * T2 * HID;    // 4718592 elements
    short* qmb = (short*)d_ws;                        // bf16 q (scaled) / ctx
    short* kmb = qmb + SZ_MERG;                       // bf16 k row-major
    short* vtb = kmb + SZ_MERG;                       // bf16 v^T [B,H,D,T2]
    short* rmb = vtb + SZ_MERG;                       // bf16 merged hidden
    short* wqb = rmb + SZ_MERG;                       // bf16 W^T [N,K] x4
    short* wkb = wqb + HID * HID;
    short* wvb = wkb + HID * HID;
    short* wob = wvb + HID * HID;
    float* k32 = (float*)d_ws;                        // fp32 k (25.2MB) overlaps
                                                      // qmb..vtb; dead by step 8
    float* metric = (float*)(wob + HID * HID);        // B*T*64 fp32
    float* node_max = metric + (size_t)BB * TT * DD;
    int* node_idx = (int*)(node_max + BB * TH);
    int* dst_idx = node_idx + BB * TH;
    int* src_tok = dst_idx + BB * RR;
    int* unm_tok = src_tok + BB * RR;
    int* counts = unm_tok + BB * UNM;
    float* part_max = (float*)(counts + BB * TH);
    int* part_idx = (int*)(part_max + (size_t)BB * TH * 32);
    float* rm = (float*)d_out;                        // merged residual in d_out

    // 0. weight transpose+bf16 (independent; wqb.. does NOT overlap k32)
    WPtrs wp;
    wp.w[0] = Wq; wp.w[1] = Wk; wp.w[2] = Wv; wp.w[3] = Wo;
    wp.wt[0] = wqb; wp.wt[1] = wkb; wp.wt[2] = wvb; wp.wt[3] = wob;
    transpose_w_kernel<<<dim3(HID / 64, HID / 64, 4), 256, 0, stream>>>(wp);

    // 1. full k = hidden @ Wk + bk (fp32, sequential-K chain — index path)
    gemm_bias<<<dim3(HID / 128, BB * TT / 128), 256, 0, stream>>>(hidden, Wk, bk, k32, BB * TT, HID, HID);

    // 2-3. metric = head-mean of k, then row-normalize (fp32)
    metric_mean_kernel<<<(BB * TT * DD + 255) / 256, 256, 0, stream>>>(k32, metric);
    metric_normalize_kernel<<<(BB * TT + 255) / 256, 256, 0, stream>>>(metric);

    // 4. scores -> partial (max, argmax), then combine
    tome_scores_part_kernel<<<dim3(8, 16, BB), 256, 0, stream>>>(metric, part_max, part_idx);
    tome_scores_combine_kernel<<<BB, 1024, 0, stream>>>(part_max, part_idx, node_max, node_idx);

    // 5-6. stable order + counts
    tome_order_kernel<<<BB, 1024, 0, stream>>>(node_max, node_idx, dst_idx, src_tok, unm_tok);
    tome_counts_kernel<<<BB, 1024, 0, stream>>>(dst_idx, counts);

    // 7. merge hidden -> rm (residual, in d_out); then bf16 copy
    merge_base_kernel<<<dim3(T2, BB), 192, 0, stream>>>(hidden, rm, unm_tok);
    merge_scatter_kernel<<<dim3(RR, BB), 256, 0, stream>>>(hidden, rm, src_tok, dst_idx);
    merge_scale_kernel<<<dim3(TH, BB), 256, 0, stream>>>(rm, counts);
    f32_to_bf16_kernel<<<(int)((SZ_MERG / 4 + 255) / 256), 256, 0, stream>>>(rm, rmb, (int)(SZ_MERG / 4));

    // 8. QKV projections via bf16 MFMA (q scaled+bf16, k bf16, v bf16-T)
    gemm_mfma<<<dim3(HID / 128, BB * T2 / 128), 256, 0, stream>>>(rmb, wqb, bq, nullptr, qmb, BB * T2, 3);
    gemm_mfma<<<dim3(HID / 128, BB * T2 / 128), 256, 0, stream>>>(rmb, wkb, bk, nullptr, kmb, BB * T2, 1);
    gemm_mfma<<<dim3(HID / 128, BB * T2 / 128), 256, 0, stream>>>(rmb, wvb, bv, nullptr, vtb, BB * T2, 2);

    // 9. MFMA flash attention (all-bf16 I/O), ctx in place of q
    attn_mfma_kernel<<<dim3(T2 / 64, HH, BB), 256, 0, stream>>>(qmb, kmb, vtb);

    // 10. out = ctx @ Wo + bo + residual (fp32 epilogue; res==C alias safe)
    gemm_mfma<<<dim3(HID / 128, BB * T2 / 128), 256, 0, stream>>>(qmb, wob, bo, rm, d_out, BB * T2, 0);

    // 11. LayerNorm in place
    ln_kernel<<<BB * T2, 256, 0, stream>>>((float*)d_out, gamma, beta);
}

// Round 11
// 542.799 us; speedup vs baseline: 1.0228x; 1.0140x over previous
//
#include <hip/hip_runtime.h>
#include <math.h>

#define BB 4
#define TT 2048
#define HH 12
#define DD 64
#define HID 768
#define RR 512
#define T2 1536
#define TH 1024   // T/2
#define UNM 512   // TH - R
#define SCALEF 0.125f

typedef short bf8v __attribute__((ext_vector_type(8)));
typedef float f4v  __attribute__((ext_vector_type(4)));

// float -> bf16 round-to-nearest-even
__device__ inline short f2bf(float f) {
    unsigned u = __float_as_uint(f);
    u += 0x7fffu + ((u >> 16) & 1u);
    return (short)(u >> 16);
}

// ---------------------------------------------------------------------------
// fp32 tiled GEMM (index path ONLY): C = A@W + bias. Sequential-K fp32 chain
// per output element (bit-exact: single accumulator, kk ascending).
// 128x64 tile (m x n), BK=16, 256 threads, 8x4/thread:
//  - per kk: 32 FMA insts vs 3 ds_read_b128 -> VALU-bound
//  - grid (12,64) = 768 blocks = 3/CU -> ~12 waves/CU latency hiding
//  - As frag reads are 4-address broadcasts (conflict-free), Bs 2-way (free)
//  - global loads for k0+16 prefetched into registers before barriers
// ---------------------------------------------------------------------------
__global__ __launch_bounds__(256) void gemm_bias(const float* __restrict__ A,
                                                 const float* __restrict__ Wt,
                                                 const float* __restrict__ bias,
                                                 float* __restrict__ C,
                                                 int M, int N, int K) {
    __shared__ float As[16][132];   // transposed A tile (k, m), padded
    __shared__ float Bs[16][68];    // B tile (k, n), padded
    int tid = threadIdx.x;
    int n0 = blockIdx.x * 64, m0 = blockIdx.y * 128;
    int tx = tid & 15, ty = tid >> 4;          // tx->n (4 cols), ty->m (2x4 rows)
    int la_m = tid >> 1, la_k = (tid & 1) << 3;
    int lb_k = tid >> 4, lb_n = (tid & 15) << 2;
    const float* ag = A + (size_t)(m0 + la_m) * K + la_k;
    const float* bg = Wt + (size_t)lb_k * N + n0 + lb_n;

    float acc[8][4] = {};
    float4 a0n = *(const float4*)(ag);
    float4 a1n = *(const float4*)(ag + 4);
    float4 b0n = *(const float4*)(bg);

    for (int k0 = 0; k0 < K; k0 += 16) {
        float4 av0 = a0n, av1 = a1n, bv0 = b0n;
        if (k0 + 16 < K) {
            a0n = *(const float4*)(ag + k0 + 16);
            a1n = *(const float4*)(ag + k0 + 20);
            b0n = *(const float4*)(bg + (size_t)(k0 + 16) * N);
        }
        __syncthreads();
        As[la_k + 0][la_m] = av0.x; As[la_k + 1][la_m] = av0.y;
        As[la_k + 2][la_m] = av0.z; As[la_k + 3][la_m] = av0.w;
        As[la_k + 4][la_m] = av1.x; As[la_k + 5][la_m] = av1.y;
        As[la_k + 6][la_m] = av1.z; As[la_k + 7][la_m] = av1.w;
        *(float4*)&Bs[lb_k][lb_n] = bv0;
        __syncthreads();
#pragma unroll
        for (int kk = 0; kk < 16; kk++) {
            float4 a0 = *(const float4*)&As[kk][ty << 2];
            float4 a1 = *(const float4*)&As[kk][64 + (ty << 2)];
            float4 b0 = *(const float4*)&Bs[kk][tx << 2];
            float ar[8] = {a0.x, a0.y, a0.z, a0.w, a1.x, a1.y, a1.z, a1.w};
            float br[4] = {b0.x, b0.y, b0.z, b0.w};
#pragma unroll
            for (int i = 0; i < 8; i++)
#pragma unroll
                for (int j = 0; j < 4; j++) acc[i][j] += ar[i] * br[j];
        }
    }
    float4 bva = *(const float4*)(bias + n0 + (tx << 2));
    float bb4[4] = {bva.x, bva.y, bva.z, bva.w};
#pragma unroll
    for (int i = 0; i < 8; i++) {
        int m = m0 + ((i < 4) ? ((ty << 2) + i) : (64 + (ty << 2) + i - 4));
        float4 v0;
        v0.x = acc[i][0] + bb4[0]; v0.y = acc[i][1] + bb4[1];
        v0.z = acc[i][2] + bb4[2]; v0.w = acc[i][3] + bb4[3];
        *(float4*)(C + (size_t)m * N + n0 + (tx << 2)) = v0;
    }
}

// ---------------------------------------------------------------------------
// Weight transpose + bf16 convert: Wt_b[n][k] = bf16(W[k][n]). 4 matrices.
// ---------------------------------------------------------------------------
struct WPtrs {
    const float* w[4];
    short* wt[4];
};

__global__ __launch_bounds__(256) void transpose_w_kernel(WPtrs p) {
    __shared__ short tile[64][65];
    const float* W = p.w[blockIdx.z];
    short* Wt = p.wt[blockIdx.z];
    int k0 = blockIdx.x * 64, n0 = blockIdx.y * 64;
    int tid = threadIdx.x;
#pragma unroll
    for (int i = 0; i < 16; i++) {
        int idx = tid + i * 256;
        int r = idx >> 6, c = idx & 63;
        tile[c][r] = f2bf(W[(size_t)(k0 + r) * HID + n0 + c]);
    }
    __syncthreads();
#pragma unroll
    for (int i = 0; i < 16; i++) {
        int idx = tid + i * 256;
        int r = idx >> 6, c = idx & 63;
        Wt[(size_t)(n0 + r) * HID + k0 + c] = tile[r][c];
    }
}

// fp32 -> bf16 elementwise (float4 granularity)
__global__ __launch_bounds__(256) void f32_to_bf16_kernel(const float* __restrict__ in,
                                                          short* __restrict__ out, int n4) {
    int i = blockIdx.x * 256 + threadIdx.x;
    if (i >= n4) return;
    float4 v = ((const float4*)in)[i];
    short4 s;
    s.x = f2bf(v.x); s.y = f2bf(v.y); s.z = f2bf(v.z); s.w = f2bf(v.w);
    ((short4*)out)[i] = s;
}

// ---------------------------------------------------------------------------
// bf16 MFMA GEMM: C = A[M,768] @ B[768,768] + bias, B given transposed bf16.
// 128x128 tile, BK=32, 4 waves. Epilogue modes 0..3 (see r8).
// ---------------------------------------------------------------------------
__global__ __launch_bounds__(256) void gemm_mfma(const short* __restrict__ A,
                                                 const short* __restrict__ Bt,
                                                 const float* __restrict__ bias,
                                                 const float* __restrict__ res,
                                                 void* __restrict__ Cout,
                                                 int M, int mode) {
    __shared__ short As[128][40];
    __shared__ short Bs[128][40];
    int tid = threadIdx.x;
    int m0 = blockIdx.y * 128, n0 = blockIdx.x * 128;
    int w = tid >> 6, lane = tid & 63, quad = lane >> 4, l = lane & 15;
    int wm = (w & 1) << 6, wn = (w >> 1) << 6;

    f4v acc[4][4];
#pragma unroll
    for (int i = 0; i < 4; i++)
#pragma unroll
        for (int j = 0; j < 4; j++) acc[i][j] = (f4v){0.f, 0.f, 0.f, 0.f};

    int srow = tid >> 1, sseg = (tid & 1) << 4;
    const short* ag = A + (size_t)(m0 + srow) * HID + sseg;
    const short* bg = Bt + (size_t)(n0 + srow) * HID + sseg;

    for (int k0 = 0; k0 < HID; k0 += 32) {
        __syncthreads();
        *(bf8v*)&As[srow][sseg]     = *(const bf8v*)(ag + k0);
        *(bf8v*)&As[srow][sseg + 8] = *(const bf8v*)(ag + k0 + 8);
        *(bf8v*)&Bs[srow][sseg]     = *(const bf8v*)(bg + k0);
        *(bf8v*)&Bs[srow][sseg + 8] = *(const bf8v*)(bg + k0 + 8);
        __syncthreads();
        bf8v af[4], bfv[4];
#pragma unroll
        for (int mt = 0; mt < 4; mt++) af[mt] = *(const bf8v*)&As[wm + mt * 16 + l][quad * 8];
#pragma unroll
        for (int nt = 0; nt < 4; nt++) bfv[nt] = *(const bf8v*)&Bs[wn + nt * 16 + l][quad * 8];
#pragma unroll
        for (int mt = 0; mt < 4; mt++)
#pragma unroll
            for (int nt = 0; nt < 4; nt++)
                acc[mt][nt] = __builtin_amdgcn_mfma_f32_16x16x32_bf16(af[mt], bfv[nt], acc[mt][nt], 0, 0, 0);
    }

    float bia[4];
#pragma unroll
    for (int nt = 0; nt < 4; nt++) bia[nt] = bias[n0 + wn + nt * 16 + l];

    if (mode == 0) {
        float* C = (float*)Cout;
#pragma unroll
        for (int mt = 0; mt < 4; mt++)
#pragma unroll
            for (int r = 0; r < 4; r++) {
                int m = m0 + wm + mt * 16 + quad * 4 + r;
#pragma unroll
                for (int nt = 0; nt < 4; nt++) {
                    int n = n0 + wn + nt * 16 + l;
                    C[(size_t)m * HID + n] = acc[mt][nt][r] + bia[nt] + res[(size_t)m * HID + n];
                }
            }
    } else if (mode == 1 || mode == 3) {
        short* C = (short*)Cout;
        float sc = (mode == 3) ? SCALEF : 1.0f;
#pragma unroll
        for (int mt = 0; mt < 4; mt++)
#pragma unroll
            for (int r = 0; r < 4; r++) {
                int m = m0 + wm + mt * 16 + quad * 4 + r;
#pragma unroll
                for (int nt = 0; nt < 4; nt++) {
                    int n = n0 + wn + nt * 16 + l;
                    C[(size_t)m * HID + n] = f2bf((acc[mt][nt][r] + bia[nt]) * sc);
                }
            }
    } else {
        short* C = (short*)Cout;
#pragma unroll
        for (int nt = 0; nt < 4; nt++) {
            int n = n0 + wn + nt * 16 + l;
            int h = n >> 6, d = n & 63;
#pragma unroll
            for (int mt = 0; mt < 4; mt++) {
                int m = m0 + wm + mt * 16 + quad * 4;
                int b = m / T2, t = m % T2;
                short4 sv;
                sv.x = f2bf(acc[mt][nt][0] + bia[nt]);
                sv.y = f2bf(acc[mt][nt][1] + bia[nt]);
                sv.z = f2bf(acc[mt][nt][2] + bia[nt]);
                sv.w = f2bf(acc[mt][nt][3] + bia[nt]);
                *(short4*)(C + (((size_t)b * HH + h) * DD + d) * T2 + t) = sv;
            }
        }
    }
}

// ---------------------------------------------------------------------------
// metric mean: metric[t,d] = (sum_{h} k[t, h*64+d]) / 12  (fp32, h ascending)
// ---------------------------------------------------------------------------
__global__ __launch_bounds__(256) void metric_mean_kernel(const float* __restrict__ k32,
                                                          float* __restrict__ metric) {
    int idx = blockIdx.x * 256 + threadIdx.x;
    if (idx >= BB * TT * DD) return;
    int t = idx >> 6, d = idx & 63;
    float s = 0.f;
#pragma unroll
    for (int h = 0; h < HH; h++) s += k32[(size_t)t * HID + h * DD + d];
    metric[idx] = s / 12.0f;
}

__global__ __launch_bounds__(256) void metric_normalize_kernel(float* __restrict__ metric) {
    int row = blockIdx.x * 256 + threadIdx.x;
    if (row >= BB * TT) return;
    float* p = metric + (size_t)row * DD;
    float ss = 0.f;
#pragma unroll
    for (int d = 0; d < DD; d++) ss += p[d] * p[d];
    float denom = sqrtf(ss) + 1e-6f;
#pragma unroll
    for (int d = 0; d < DD; d++) p[d] = p[d] / denom;
}

// ---------------------------------------------------------------------------
// Partial scores: grid (8 j-splits, 16 i-tiles, B), block 256 (4 waves).
// ---------------------------------------------------------------------------
__global__ __launch_bounds__(256) void tome_scores_part_kernel(const float* __restrict__ metric,
                                                               float* __restrict__ part_max,
                                                               int* __restrict__ part_idx) {
    int b = blockIdx.z;
    int i0 = blockIdx.y * 64;
    int jbase = blockIdx.x * 128;
    int tid = threadIdx.x;
    int il = tid & 63, w = tid >> 6;
    __shared__ float b_lds[64][68];

    const float* arow = metric + ((size_t)b * TT + 2 * (i0 + il)) * DD;
    float4 areg[16];
#pragma unroll
    for (int t = 0; t < 16; t++) areg[t] = ((const float4*)arow)[t];

    float best = -INFINITY;
    int bidx = 0;
    for (int c = 0; c < 2; c++) {
        __syncthreads();
        {
            int r = tid >> 2, cb = (tid & 3) << 4;
            const float* src = metric + ((size_t)b * TT + 2 * (jbase + c * 64 + r) + 1) * DD + cb;
#pragma unroll
            for (int t = 0; t < 4; t++)
                *(float4*)&b_lds[r][cb + 4 * t] = ((const float4*)src)[t];
        }
        __syncthreads();
#pragma unroll
        for (int jj = 0; jj < 16; jj++) {
            int jr = w * 16 + jj;
            float acc = 0.f;
#pragma unroll
            for (int t = 0; t < 16; t++) {
                float4 bv = *(const float4*)&b_lds[jr][t * 4];
                acc += areg[t].x * bv.x;
                acc += areg[t].y * bv.y;
                acc += areg[t].z * bv.z;
                acc += areg[t].w * bv.w;
            }
            int j = jbase + c * 64 + jr;
            if (acc > best) { best = acc; bidx = j; }
        }
    }
    int slot = ((b * TH + i0 + il) << 5) + (blockIdx.x << 2) + w;
    part_max[slot] = best;
    part_idx[slot] = bidx;
}

__global__ __launch_bounds__(1024) void tome_scores_combine_kernel(const float* __restrict__ part_max,
                                                                   const int* __restrict__ part_idx,
                                                                   float* __restrict__ node_max,
                                                                   int* __restrict__ node_idx) {
    int b = blockIdx.x, i = threadIdx.x;
    int base = (b * TH + i) << 5;
    float bv = part_max[base];
    int bi = part_idx[base];
#pragma unroll
    for (int p = 1; p < 32; p++) {
        float v = part_max[base + p];
        int vi = part_idx[base + p];
        if (v > bv || (v == bv && vi < bi)) { bv = v; bi = vi; }
    }
    node_max[b * TH + i] = bv;
    node_idx[b * TH + i] = bi;
}

// ---------------------------------------------------------------------------
// Stable descending argsort via rank counting. grid B, block 1024.
// ---------------------------------------------------------------------------
__global__ __launch_bounds__(1024) void tome_order_kernel(const float* __restrict__ node_max,
                                                          const int* __restrict__ node_idx,
                                                          int* __restrict__ dst_idx,
                                                          int* __restrict__ src_tok,
                                                          int* __restrict__ unm_tok) {
    __shared__ float vals[TH];
    int b = blockIdx.x;
    int i = threadIdx.x;
    vals[i] = node_max[b * TH + i];
    __syncthreads();
    float v = vals[i];
    int rank = 0;
    for (int j = 0; j < TH; j++) {
        float vj = vals[j];
        rank += (vj > v || (vj == v && j < i)) ? 1 : 0;
    }
    if (rank < RR) {
        src_tok[b * RR + rank] = i;
        dst_idx[b * RR + rank] = node_idx[b * TH + i];
    } else {
        unm_tok[b * UNM + (rank - RR)] = i;
    }
}

__global__ __launch_bounds__(1024) void tome_counts_kernel(const int* __restrict__ dst_idx,
                                                           int* __restrict__ counts) {
    __shared__ int c[TH];
    int b = blockIdx.x;
    int i = threadIdx.x;
    c[i] = 0;
    __syncthreads();
    if (i < RR) atomicAdd(&c[dst_idx[b * RR + i]], 1);
    __syncthreads();
    counts[b * TH + i] = c[i];
}

// ---------------------------------------------------------------------------
// Merge hidden only (merge commutes with affine maps; avg weights sum to 1).
// ---------------------------------------------------------------------------
__global__ __launch_bounds__(192) void merge_base_kernel(const float* __restrict__ in,
                                                         float* __restrict__ out,
                                                         const int* __restrict__ unm_tok) {
    int t = blockIdx.x, b = blockIdx.y;
    int src_row = (t < UNM) ? 2 * unm_tok[b * UNM + t] : 2 * (t - UNM) + 1;
    const float4* src = (const float4*)(in + ((size_t)b * TT + src_row) * HID);
    float4* dst = (float4*)(out + ((size_t)b * T2 + t) * HID);
    dst[threadIdx.x] = src[threadIdx.x];
}

__global__ __launch_bounds__(256) void merge_scatter_kernel(const float* __restrict__ in,
                                                            float* __restrict__ out,
                                                            const int* __restrict__ src_tok,
                                                            const int* __restrict__ dst_idx) {
    int s = blockIdx.x, b = blockIdx.y;
    int srow = 2 * src_tok[b * RR + s];
    int drow = UNM + dst_idx[b * RR + s];
    const float* src = in + ((size_t)b * TT + srow) * HID;
    float* dst = out + ((size_t)b * T2 + drow) * HID;
#pragma unroll
    for (int c = threadIdx.x; c < HID; c += 256) atomicAdd(&dst[c], src[c]);
}

__global__ __launch_bounds__(256) void merge_scale_kernel(float* __restrict__ out,
                                                          const int* __restrict__ counts) {
    int r = blockIdx.x, b = blockIdx.y;
    float inv = 1.0f / (1.0f + (float)counts[b * TH + r]);
    float* dst = out + ((size_t)b * T2 + UNM + r) * HID;
#pragma unroll
    for (int c = threadIdx.x; c < HID; c += 256) dst[c] *= inv;
}

// ---------------------------------------------------------------------------
// MFMA bf16 flash attention, transposed form (S^T / O^T). All-bf16 I/O.
// ---------------------------------------------------------------------------
__global__ __launch_bounds__(256) void attn_mfma_kernel(short* __restrict__ qmb,
                                                        const short* __restrict__ kmb,
                                                        const short* __restrict__ vtb) {
    __shared__ short Ks[64][72];
    __shared__ short Vts[64][72];
    __shared__ short Pt[4][16][72];

    const int b = blockIdx.z, h = blockIdx.y;
    const int tid = threadIdx.x;
    const int w = tid >> 6;
    const int lane = tid & 63;
    const int quad = lane >> 4;
    const int l = lane & 15;
    const int q0 = blockIdx.x * 64 + w * 16;

    short* qp = qmb + ((size_t)b * T2 + q0 + l) * HID + h * DD;
    bf8v bq0 = *(const bf8v*)(qp + quad * 8);
    bf8v bq1 = *(const bf8v*)(qp + 32 + quad * 8);

    f4v O[4];
#pragma unroll
    for (int t = 0; t < 4; t++) O[t] = (f4v){0.f, 0.f, 0.f, 0.f};
    float m_st = -INFINITY, l_st = 0.f;

    const int rstg = tid >> 2;
    const int cstg = (tid & 3) << 4;
    const short* kbase = kmb + (size_t)b * T2 * HID + h * DD;
    const short* vbase = vtb + (((size_t)b * HH + h) * DD + rstg) * T2;

    for (int c0 = 0; c0 < T2; c0 += 64) {
        __syncthreads();
        {
            const short* ksrc = kbase + (size_t)(c0 + rstg) * HID + cstg;
            *(bf8v*)&Ks[rstg][cstg]     = *(const bf8v*)ksrc;
            *(bf8v*)&Ks[rstg][cstg + 8] = *(const bf8v*)(ksrc + 8);
            const short* vsrc = vbase + c0 + cstg;
            *(bf8v*)&Vts[rstg][cstg]     = *(const bf8v*)vsrc;
            *(bf8v*)&Vts[rstg][cstg + 8] = *(const bf8v*)(vsrc + 8);
        }
        __syncthreads();

        f4v s[4];
#pragma unroll
        for (int t = 0; t < 4; t++) {
            bf8v ak0 = *(const bf8v*)&Ks[t * 16 + l][quad * 8];
            bf8v ak1 = *(const bf8v*)&Ks[t * 16 + l][32 + quad * 8];
            f4v acc = (f4v){0.f, 0.f, 0.f, 0.f};
            acc = __builtin_amdgcn_mfma_f32_16x16x32_bf16(ak0, bq0, acc, 0, 0, 0);
            acc = __builtin_amdgcn_mfma_f32_16x16x32_bf16(ak1, bq1, acc, 0, 0, 0);
            s[t] = acc;
        }

        float mx = s[0][0];
#pragma unroll
        for (int t = 0; t < 4; t++)
#pragma unroll
            for (int r = 0; r < 4; r++) mx = fmaxf(mx, s[t][r]);
        mx = fmaxf(mx, __shfl_xor(mx, 16));
        mx = fmaxf(mx, __shfl_xor(mx, 32));
        float mnew = fmaxf(m_st, mx);
        float alpha = __expf(m_st - mnew);
        float p[4][4];
        float sum = 0.f;
#pragma unroll
        for (int t = 0; t < 4; t++)
#pragma unroll
            for (int r = 0; r < 4; r++) {
                float pv = __expf(s[t][r] - mnew);
                p[t][r] = pv;
                sum += pv;
            }
        sum += __shfl_xor(sum, 16);
        sum += __shfl_xor(sum, 32);
        l_st = l_st * alpha + sum;
        m_st = mnew;
#pragma unroll
        for (int t = 0; t < 4; t++) {
            O[t][0] *= alpha; O[t][1] *= alpha; O[t][2] *= alpha; O[t][3] *= alpha;
        }

#pragma unroll
        for (int t = 0; t < 4; t++) {
            short4 pv;
            pv.x = f2bf(p[t][0]); pv.y = f2bf(p[t][1]);
            pv.z = f2bf(p[t][2]); pv.w = f2bf(p[t][3]);
            *(short4*)&Pt[w][l][t * 16 + quad * 4] = pv;
        }

        {
            bf8v bp0 = *(const bf8v*)&Pt[w][l][quad * 8];
            bf8v bp1 = *(const bf8v*)&Pt[w][l][32 + quad * 8];
#pragma unroll
            for (int t = 0; t < 4; t++) {
                bf8v av0 = *(const bf8v*)&Vts[t * 16 + l][quad * 8];
                bf8v av1 = *(const bf8v*)&Vts[t * 16 + l][32 + quad * 8];
                O[t] = __builtin_amdgcn_mfma_f32_16x16x32_bf16(av0, bp0, O[t], 0, 0, 0);
                O[t] = __builtin_amdgcn_mfma_f32_16x16x32_bf16(av1, bp1, O[t], 0, 0, 0);
            }
        }
    }

    float inv = 1.0f / l_st;
#pragma unroll
    for (int t = 0; t < 4; t++) {
        short4 ov;
        ov.x = f2bf(O[t][0] * inv); ov.y = f2bf(O[t][1] * inv);
        ov.z = f2bf(O[t][2] * inv); ov.w = f2bf(O[t][3] * inv);
        *(short4*)(qp + t * 16 + quad * 4) = ov;
    }
}

// ---------------------------------------------------------------------------
// LayerNorm in place: grid B*T2 rows, block 256 (each thread 3 cols)
// ---------------------------------------------------------------------------
__global__ __launch_bounds__(256) void ln_kernel(float* __restrict__ out,
                                                 const float* __restrict__ gamma,
                                                 const float* __restrict__ beta) {
    int row = blockIdx.x;
    int tid = threadIdx.x;
    float* p = out + (size_t)row * HID;
    float x[3];
#pragma unroll
    for (int i = 0; i < 3; i++) x[i] = p[tid + i * 256];
    float s = x[0] + x[1] + x[2];
#pragma unroll
    for (int off = 1; off < 64; off <<= 1) s += __shfl_xor(s, off);
    __shared__ float sb[4];
    int wid = tid >> 6;
    if ((tid & 63) == 0) sb[wid] = s;
    __syncthreads();
    float mu = (sb[0] + sb[1] + sb[2] + sb[3]) * (1.0f / HID);
    float vs = 0.f;
#pragma unroll
    for (int i = 0; i < 3; i++) {
        float d = x[i] - mu;
        vs += d * d;
    }
#pragma unroll
    for (int off = 1; off < 64; off <<= 1) vs += __shfl_xor(vs, off);
    __syncthreads();
    if ((tid & 63) == 0) sb[wid] = vs;
    __syncthreads();
    float var = (sb[0] + sb[1] + sb[2] + sb[3]) * (1.0f / HID);
    float inv = rsqrtf(var + 1e-12f);
#pragma unroll
    for (int i = 0; i < 3; i++) {
        int c = tid + i * 256;
        p[c] = (x[i] - mu) * inv * gamma[c] + beta[c];
    }
}

// ---------------------------------------------------------------------------
extern "C" void kernel_launch(void* const* d_in, const int* in_sizes, int n_in,
                              void* d_out, int out_size, void* d_ws, size_t ws_size,
                              hipStream_t stream) {
    const float* hidden = (const float*)d_in[0];
    const float* Wq = (const float*)d_in[1];
    const float* bq = (const float*)d_in[2];
    const float* Wk = (const float*)d_in[3];
    const float* bk = (const float*)d_in[4];
    const float* Wv = (const float*)d_in[5];
    const float* bv = (const float*)d_in[6];
    const float* Wo = (const float*)d_in[7];
    const float* bo = (const float*)d_in[8];
    const float* gamma = (const float*)d_in[9];
    const float* beta = (const float*)d_in[10];

    const size_t SZ_MERG = (size_t)BB * T2 * HID;    // 4718592 elements
    short* qmb = (short*)d_ws;                        // bf16 q (scaled) / ctx
    short* kmb = qmb + SZ_MERG;                       // bf16 k row-major
    short* vtb = kmb + SZ_MERG;                       // bf16 v^T [B,H,D,T2]
    short* rmb = vtb + SZ_MERG;                       // bf16 merged hidden
    short* wqb = rmb + SZ_MERG;                       // bf16 W^T [N,K] x4
    short* wkb = wqb + HID * HID;
    short* wvb = wkb + HID * HID;
    short* wob = wvb + HID * HID;
    float* k32 = (float*)d_ws;                        // fp32 k (25.2MB) overlaps
                                                      // qmb..vtb; dead by step 8
    float* metric = (float*)(wob + HID * HID);        // B*T*64 fp32
    float* node_max = metric + (size_t)BB * TT * DD;
    int* node_idx = (int*)(node_max + BB * TH);
    int* dst_idx = node_idx + BB * TH;
    int* src_tok = dst_idx + BB * RR;
    int* unm_tok = src_tok + BB * RR;
    int* counts = unm_tok + BB * UNM;
    float* part_max = (float*)(counts + BB * TH);
    int* part_idx = (int*)(part_max + (size_t)BB * TH * 32);
    float* rm = (float*)d_out;                        // merged residual in d_out

    // 0. weight transpose+bf16 (independent; wqb.. does NOT overlap k32)
    WPtrs wp;
    wp.w[0] = Wq; wp.w[1] = Wk; wp.w[2] = Wv; wp.w[3] = Wo;
    wp.wt[0] = wqb; wp.wt[1] = wkb; wp.wt[2] = wvb; wp.wt[3] = wob;
    transpose_w_kernel<<<dim3(HID / 64, HID / 64, 4), 256, 0, stream>>>(wp);

    // 1. full k = hidden @ Wk + bk (fp32, sequential-K chain — index path)
    gemm_bias<<<dim3(HID / 64, BB * TT / 128), 256, 0, stream>>>(hidden, Wk, bk, k32, BB * TT, HID, HID);

    // 2-3. metric = head-mean of k, then row-normalize (fp32)
    metric_mean_kernel<<<(BB * TT * DD + 255) / 256, 256, 0, stream>>>(k32, metric);
    metric_normalize_kernel<<<(BB * TT + 255) / 256, 256, 0, stream>>>(metric);

    // 4. scores -> partial (max, argmax), then combine
    tome_scores_part_kernel<<<dim3(8, 16, BB), 256, 0, stream>>>(metric, part_max, part_idx);
    tome_scores_combine_kernel<<<BB, 1024, 0, stream>>>(part_max, part_idx, node_max, node_idx);

    // 5-6. stable order + counts
    tome_order_kernel<<<BB, 1024, 0, stream>>>(node_max, node_idx, dst_idx, src_tok, unm_tok);
    tome_counts_kernel<<<BB, 1024, 0, stream>>>(dst_idx, counts);

    // 7. merge hidden -> rm (residual, in d_out); then bf16 copy
    merge_base_kernel<<<dim3(T2, BB), 192, 0, stream>>>(hidden, rm, unm_tok);
    merge_scatter_kernel<<<dim3(RR, BB), 256, 0, stream>>>(hidden, rm, src_tok, dst_idx);
    merge_scale_kernel<<<dim3(TH, BB), 256, 0, stream>>>(rm, counts);
    f32_to_bf16_kernel<<<(int)((SZ_MERG / 4 + 255) / 256), 256, 0, stream>>>(rm, rmb, (int)(SZ_MERG / 4));

    // 8. QKV projections via bf16 MFMA (q scaled+bf16, k bf16, v bf16-T)
    gemm_mfma<<<dim3(HID / 128, BB * T2 / 128), 256, 0, stream>>>(rmb, wqb, bq, nullptr, qmb, BB * T2, 3);
    gemm_mfma<<<dim3(HID / 128, BB * T2 / 128), 256, 0, stream>>>(rmb, wkb, bk, nullptr, kmb, BB * T2, 1);
    gemm_mfma<<<dim3(HID / 128, BB * T2 / 128), 256, 0, stream>>>(rmb, wvb, bv, nullptr, vtb, BB * T2, 2);

    // 9. MFMA flash attention (all-bf16 I/O), ctx in place of q
    attn_mfma_kernel<<<dim3(T2 / 64, HH, BB), 256, 0, stream>>>(qmb, kmb, vtb);

    // 10. out = ctx @ Wo + bo + residual (fp32 epilogue; res==C alias safe)
    gemm_mfma<<<dim3(HID / 128, BB * T2 / 128), 256, 0, stream>>>(qmb, wob, bo, rm, d_out, BB * T2, 0);

    // 11. LayerNorm in place
    ln_kernel<<<BB * T2, 256, 0, stream>>>((float*)d_out, gamma, beta);
}